// Round 4
// baseline (458.463 us; speedup 1.0000x reference)
//
#include <hip/hip_runtime.h>

// Problem constants (from reference setup_inputs):
//   points:     (B, 3, H, W)  f32
//   masks:      (B, K, H, W)  f32
//   transforms: (B, K, 3, 4)  f32
//   out:        (B, 3, H, W)  f32
constexpr int B = 16;
constexpr int K = 16;
constexpr int H = 480;
constexpr int W = 640;
constexpr int HW = H * W;                 // 307200, divisible by 4
constexpr int BLOCK = 256;
constexpr int QUADS_PER_B = HW / 4;       // 76800
constexpr int BLOCKS_PER_B = QUADS_PER_B / BLOCK;  // 300 exactly

__global__ __launch_bounds__(BLOCK) void ntfm3d_kernel(
    const float* __restrict__ points,
    const float* __restrict__ masks,
    const float* __restrict__ transforms,
    float* __restrict__ out)
{
    __shared__ float tf[K * 12];

    const int b     = blockIdx.x / BLOCKS_PER_B;   // uniform per block
    const int chunk = blockIdx.x % BLOCKS_PER_B;

    // Stage this batch's K*3*4 transform params into LDS (768 B).
    if (threadIdx.x < K * 12)
        tf[threadIdx.x] = transforms[(size_t)b * K * 12 + threadIdx.x];
    __syncthreads();

    const int q = chunk * BLOCK + (int)threadIdx.x;  // quad index within batch
    const int p = q * 4;                             // pixel index within batch

    const float* pb = points + (size_t)b * 3 * HW + p;
    const float4 px = *reinterpret_cast<const float4*>(pb);
    const float4 py = *reinterpret_cast<const float4*>(pb + HW);
    const float4 pz = *reinterpret_cast<const float4*>(pb + 2 * HW);

    float4 acc0 = {0.f, 0.f, 0.f, 0.f};
    float4 acc1 = {0.f, 0.f, 0.f, 0.f};
    float4 acc2 = {0.f, 0.f, 0.f, 0.f};

    const float* mb = masks + (size_t)b * K * HW + p;

    #pragma unroll
    for (int k = 0; k < K; ++k) {
        const float4 m = *reinterpret_cast<const float4*>(mb + (size_t)k * HW);
        const float* R = &tf[k * 12];
        const float r00 = R[0], r01 = R[1],  r02 = R[2],  t0 = R[3];
        const float r10 = R[4], r11 = R[5],  r12 = R[6],  t1 = R[7];
        const float r20 = R[8], r21 = R[9],  r22 = R[10], t2 = R[11];

        #define LANE(j)                                                   \
        {                                                                 \
            float sx = fmaf(r02, pz.j, fmaf(r01, py.j, fmaf(r00, px.j, t0))); \
            float sy = fmaf(r12, pz.j, fmaf(r11, py.j, fmaf(r10, px.j, t1))); \
            float sz = fmaf(r22, pz.j, fmaf(r21, py.j, fmaf(r20, px.j, t2))); \
            acc0.j = fmaf(m.j, sx, acc0.j);                               \
            acc1.j = fmaf(m.j, sy, acc1.j);                               \
            acc2.j = fmaf(m.j, sz, acc2.j);                               \
        }
        LANE(x) LANE(y) LANE(z) LANE(w)
        #undef LANE
    }

    float* ob = out + (size_t)b * 3 * HW + p;
    *reinterpret_cast<float4*>(ob)          = acc0;
    *reinterpret_cast<float4*>(ob + HW)     = acc1;
    *reinterpret_cast<float4*>(ob + 2 * HW) = acc2;
}

extern "C" void kernel_launch(void* const* d_in, const int* in_sizes, int n_in,
                              void* d_out, int out_size, void* d_ws, size_t ws_size,
                              hipStream_t stream) {
    const float* points     = (const float*)d_in[0];
    const float* masks      = (const float*)d_in[1];
    const float* transforms = (const float*)d_in[2];
    float* out              = (float*)d_out;

    const int grid = B * BLOCKS_PER_B;  // 4800 blocks
    ntfm3d_kernel<<<grid, BLOCK, 0, stream>>>(points, masks, transforms, out);
}

// Round 7
// 450.297 us; speedup vs baseline: 1.0181x; 1.0181x over previous
//
#include <hip/hip_runtime.h>

// NTfm3D: out[b,c,p] = sum_k masks[b,k,p] * (R[b,k,c,:] . points[b,:,p] + t[b,k,c])
//   points:     (B, 3, H, W)  f32
//   masks:      (B, K, H, W)  f32
//   transforms: (B, K, 3, 4)  f32
//   out:        (B, 3, H, W)  f32
constexpr int B = 16;
constexpr int K = 16;
constexpr int H = 480;
constexpr int W = 640;
constexpr int HW = H * W;                        // 307200
constexpr int BLOCK = 256;
constexpr int PIX_PER_BLOCK = BLOCK * 8;         // 2048 pixels (2 quads/thread)
constexpr int BLOCKS_PER_B = HW / PIX_PER_BLOCK; // 150 exactly
constexpr int QSTRIDE = BLOCK * 4;               // 1024 pixels between a thread's quads

// Native clang vector type — required by __builtin_nontemporal_load/store.
typedef float f32x4 __attribute__((ext_vector_type(4)));

__global__ __launch_bounds__(BLOCK) void ntfm3d_kernel(
    const float* __restrict__ points,
    const float* __restrict__ masks,
    const float* __restrict__ transforms,
    float* __restrict__ out)
{
    // b is uniform per block; readfirstlane tells the compiler so transform
    // reads below become s_load (scalar cache), not per-lane vector loads.
    const int b     = __builtin_amdgcn_readfirstlane((int)(blockIdx.x / BLOCKS_PER_B));
    const int chunk = (int)(blockIdx.x % BLOCKS_PER_B);

    const int p0 = chunk * PIX_PER_BLOCK + (int)threadIdx.x * 4;  // quad 0
    // quad 1 at p0 + QSTRIDE (still wave-coalesced)

    const float* __restrict__ tfb = transforms + (size_t)b * (K * 12);

    const float* pb = points + (size_t)b * 3 * HW + p0;
    const f32x4 px0 = *reinterpret_cast<const f32x4*>(pb);
    const f32x4 px1 = *reinterpret_cast<const f32x4*>(pb + QSTRIDE);
    const f32x4 py0 = *reinterpret_cast<const f32x4*>(pb + HW);
    const f32x4 py1 = *reinterpret_cast<const f32x4*>(pb + HW + QSTRIDE);
    const f32x4 pz0 = *reinterpret_cast<const f32x4*>(pb + 2 * HW);
    const f32x4 pz1 = *reinterpret_cast<const f32x4*>(pb + 2 * HW + QSTRIDE);

    f32x4 a00 = {0.f,0.f,0.f,0.f}, a01 = {0.f,0.f,0.f,0.f}, a02 = {0.f,0.f,0.f,0.f};
    f32x4 a10 = {0.f,0.f,0.f,0.f}, a11 = {0.f,0.f,0.f,0.f}, a12 = {0.f,0.f,0.f,0.f};

    const float* mb = masks + (size_t)b * K * HW + p0;

    #pragma unroll
    for (int k = 0; k < K; ++k) {
        // masks: zero-reuse stream -> nontemporal
        const f32x4 m0 = __builtin_nontemporal_load(
            reinterpret_cast<const f32x4*>(mb + (size_t)k * HW));
        const f32x4 m1 = __builtin_nontemporal_load(
            reinterpret_cast<const f32x4*>(mb + (size_t)k * HW + QSTRIDE));

        // wave-uniform scalar loads (s_load) of this k's 3x4 transform
        const float r00 = tfb[k*12+0], r01 = tfb[k*12+1],  r02 = tfb[k*12+2],  t0 = tfb[k*12+3];
        const float r10 = tfb[k*12+4], r11 = tfb[k*12+5],  r12 = tfb[k*12+6],  t1 = tfb[k*12+7];
        const float r20 = tfb[k*12+8], r21 = tfb[k*12+9],  r22 = tfb[k*12+10], t2 = tfb[k*12+11];

        #define LANE(M, PX, PY, PZ, A0, A1, A2, j)                              \
        {                                                                       \
            float sx = fmaf(r02, PZ.j, fmaf(r01, PY.j, fmaf(r00, PX.j, t0)));   \
            float sy = fmaf(r12, PZ.j, fmaf(r11, PY.j, fmaf(r10, PX.j, t1)));   \
            float sz = fmaf(r22, PZ.j, fmaf(r21, PY.j, fmaf(r20, PX.j, t2)));   \
            A0.j = fmaf(M.j, sx, A0.j);                                         \
            A1.j = fmaf(M.j, sy, A1.j);                                         \
            A2.j = fmaf(M.j, sz, A2.j);                                         \
        }
        LANE(m0, px0, py0, pz0, a00, a01, a02, x)
        LANE(m0, px0, py0, pz0, a00, a01, a02, y)
        LANE(m0, px0, py0, pz0, a00, a01, a02, z)
        LANE(m0, px0, py0, pz0, a00, a01, a02, w)
        LANE(m1, px1, py1, pz1, a10, a11, a12, x)
        LANE(m1, px1, py1, pz1, a10, a11, a12, y)
        LANE(m1, px1, py1, pz1, a10, a11, a12, z)
        LANE(m1, px1, py1, pz1, a10, a11, a12, w)
        #undef LANE
    }

    float* ob = out + (size_t)b * 3 * HW + p0;
    __builtin_nontemporal_store(a00, reinterpret_cast<f32x4*>(ob));
    __builtin_nontemporal_store(a10, reinterpret_cast<f32x4*>(ob + QSTRIDE));
    __builtin_nontemporal_store(a01, reinterpret_cast<f32x4*>(ob + HW));
    __builtin_nontemporal_store(a11, reinterpret_cast<f32x4*>(ob + HW + QSTRIDE));
    __builtin_nontemporal_store(a02, reinterpret_cast<f32x4*>(ob + 2 * HW));
    __builtin_nontemporal_store(a12, reinterpret_cast<f32x4*>(ob + 2 * HW + QSTRIDE));
}

extern "C" void kernel_launch(void* const* d_in, const int* in_sizes, int n_in,
                              void* d_out, int out_size, void* d_ws, size_t ws_size,
                              hipStream_t stream) {
    const float* points     = (const float*)d_in[0];
    const float* masks      = (const float*)d_in[1];
    const float* transforms = (const float*)d_in[2];
    float* out              = (float*)d_out;

    const int grid = B * BLOCKS_PER_B;  // 2400 blocks
    ntfm3d_kernel<<<grid, BLOCK, 0, stream>>>(points, masks, transforms, out);
}

// Round 8
// 437.369 us; speedup vs baseline: 1.0482x; 1.0296x over previous
//
#include <hip/hip_runtime.h>

// NTfm3D: out[b,c,p] = sum_k masks[b,k,p] * (R[b,k,c,:] . points[b,:,p] + t[b,k,c])
//   points (B,3,H,W) f32 | masks (B,K,H,W) f32 | transforms (B,K,3,4) f32 | out (B,3,H,W) f32
constexpr int B = 16;
constexpr int K = 16;
constexpr int H = 480;
constexpr int W = 640;
constexpr int HW = H * W;                        // 307200
constexpr int BLOCK = 256;
constexpr int PIX_PER_BLOCK = BLOCK * 8;         // 2048 pixels (2 quads/thread)
constexpr int BLOCKS_PER_B = HW / PIX_PER_BLOCK; // 150 exactly
constexpr int QSTRIDE = BLOCK * 4;               // 1024 pixels between a thread's quads

typedef float f32x4 __attribute__((ext_vector_type(4)));

__device__ __forceinline__ f32x4 ntload(const float* p) {
    return __builtin_nontemporal_load(reinterpret_cast<const f32x4*>(p));
}

__global__ __launch_bounds__(BLOCK) void ntfm3d_kernel(
    const float* __restrict__ points,
    const float* __restrict__ masks,
    const float* __restrict__ transforms,
    float* __restrict__ out)
{
    const int b     = __builtin_amdgcn_readfirstlane((int)(blockIdx.x / BLOCKS_PER_B));
    const int chunk = (int)(blockIdx.x % BLOCKS_PER_B);
    const int p0    = chunk * PIX_PER_BLOCK + (int)threadIdx.x * 4;

    const float* __restrict__ tfb = transforms + (size_t)b * (K * 12);

    const float* pb = points + (size_t)b * 3 * HW + p0;
    const f32x4 px0 = ntload(pb);
    const f32x4 px1 = ntload(pb + QSTRIDE);
    const f32x4 py0 = ntload(pb + HW);
    const f32x4 py1 = ntload(pb + HW + QSTRIDE);
    const f32x4 pz0 = ntload(pb + 2 * HW);
    const f32x4 pz1 = ntload(pb + 2 * HW + QSTRIDE);

    f32x4 a00 = {0.f,0.f,0.f,0.f}, a01 = {0.f,0.f,0.f,0.f}, a02 = {0.f,0.f,0.f,0.f};
    f32x4 a10 = {0.f,0.f,0.f,0.f}, a11 = {0.f,0.f,0.f,0.f}, a12 = {0.f,0.f,0.f,0.f};

    const float* mb = masks + (size_t)b * K * HW + p0;

    // COMPUTE one k-plane for both quads; transforms via wave-uniform s_load.
    #define COMPUTE(kk, M0, M1)                                                   \
    {                                                                             \
        const float* Rr = tfb + (kk) * 12;                                        \
        const float r00 = Rr[0], r01 = Rr[1], r02 = Rr[2],  t0 = Rr[3];           \
        const float r10 = Rr[4], r11 = Rr[5], r12 = Rr[6],  t1 = Rr[7];           \
        const float r20 = Rr[8], r21 = Rr[9], r22 = Rr[10], t2 = Rr[11];          \
        _Pragma("unroll")                                                         \
        for (int j = 0; j < 4; ++j) {                                             \
            float sx0 = fmaf(r02, pz0[j], fmaf(r01, py0[j], fmaf(r00, px0[j], t0))); \
            float sy0 = fmaf(r12, pz0[j], fmaf(r11, py0[j], fmaf(r10, px0[j], t1))); \
            float sz0 = fmaf(r22, pz0[j], fmaf(r21, py0[j], fmaf(r20, px0[j], t2))); \
            a00[j] = fmaf(M0[j], sx0, a00[j]);                                    \
            a01[j] = fmaf(M0[j], sy0, a01[j]);                                    \
            a02[j] = fmaf(M0[j], sz0, a02[j]);                                    \
            float sx1 = fmaf(r02, pz1[j], fmaf(r01, py1[j], fmaf(r00, px1[j], t0))); \
            float sy1 = fmaf(r12, pz1[j], fmaf(r11, py1[j], fmaf(r10, px1[j], t1))); \
            float sz1 = fmaf(r22, pz1[j], fmaf(r21, py1[j], fmaf(r20, px1[j], t2))); \
            a10[j] = fmaf(M1[j], sx1, a10[j]);                                    \
            a11[j] = fmaf(M1[j], sy1, a11[j]);                                    \
            a12[j] = fmaf(M1[j], sz1, a12[j]);                                    \
        }                                                                         \
    }

    // Software pipeline over k: hold 2 pairs (k, k+1) in regs, prefetch (k+2, k+3).
    f32x4 m00 = ntload(mb);
    f32x4 m01 = ntload(mb + QSTRIDE);
    f32x4 m10 = ntload(mb + (size_t)HW);
    f32x4 m11 = ntload(mb + (size_t)HW + QSTRIDE);

    #pragma unroll 1
    for (int i = 0; i < 7; ++i) {
        const int k = 2 * i;
        const float* nb0 = mb + (size_t)(k + 2) * HW;
        const float* nb1 = mb + (size_t)(k + 3) * HW;
        f32x4 n00 = ntload(nb0);
        f32x4 n01 = ntload(nb0 + QSTRIDE);
        f32x4 n10 = ntload(nb1);
        f32x4 n11 = ntload(nb1 + QSTRIDE);

        COMPUTE(k,     m00, m01);
        COMPUTE(k + 1, m10, m11);

        m00 = n00; m01 = n01; m10 = n10; m11 = n11;
    }
    COMPUTE(14, m00, m01);
    COMPUTE(15, m10, m11);
    #undef COMPUTE

    float* ob = out + (size_t)b * 3 * HW + p0;
    __builtin_nontemporal_store(a00, reinterpret_cast<f32x4*>(ob));
    __builtin_nontemporal_store(a10, reinterpret_cast<f32x4*>(ob + QSTRIDE));
    __builtin_nontemporal_store(a01, reinterpret_cast<f32x4*>(ob + HW));
    __builtin_nontemporal_store(a11, reinterpret_cast<f32x4*>(ob + HW + QSTRIDE));
    __builtin_nontemporal_store(a02, reinterpret_cast<f32x4*>(ob + 2 * HW));
    __builtin_nontemporal_store(a12, reinterpret_cast<f32x4*>(ob + 2 * HW + QSTRIDE));
}

extern "C" void kernel_launch(void* const* d_in, const int* in_sizes, int n_in,
                              void* d_out, int out_size, void* d_ws, size_t ws_size,
                              hipStream_t stream) {
    const float* points     = (const float*)d_in[0];
    const float* masks      = (const float*)d_in[1];
    const float* transforms = (const float*)d_in[2];
    float* out              = (float*)d_out;

    const int grid = B * BLOCKS_PER_B;  // 2400 blocks
    ntfm3d_kernel<<<grid, BLOCK, 0, stream>>>(points, masks, transforms, out);
}